// Round 7
// baseline (337.106 us; speedup 1.0000x reference)
//
#include <hip/hip_runtime.h>
#include <hip/hip_bf16.h>
#include <math.h>

#define H 511
#define L 2048
#define NST 32
#define NLAYERS 4
#define LN_EPS 1e-5f
#define NCHUNK 16
#define TCH (L / NCHUNK)   // 128
#define HN (H * NST)       // 16352
#define HP 512             // K padded
#define GBK 64
#define GBN 64
#define NSTRIPE 16         // LN h-stripes of 32

typedef __attribute__((ext_vector_type(8))) short short8;
typedef __attribute__((ext_vector_type(4))) float f32x4;

__device__ __forceinline__ ushort f2bf(float v) {
    __hip_bfloat16 b = __float2bfloat16(v);
    return *reinterpret_cast<ushort*>(&b);
}

// ---------------------------------------------------------------------------
// Merged precompute: per-(h,n) coefs (idx < HN) + W->bf16 pad (idx < 2H*HP).
// ---------------------------------------------------------------------------
__global__ __launch_bounds__(256) void pre_kernel(
    const float* __restrict__ log_dt,
    const float* __restrict__ A_real_log,
    const float* __restrict__ A_imag,
    const float* __restrict__ C_re,
    const float* __restrict__ C_im,
    const float* __restrict__ W,
    float* __restrict__ wr_o, float* __restrict__ wi_o,
    float* __restrict__ cr_o, float* __restrict__ ci_o,
    ushort* __restrict__ wbf)
{
    int idx = blockIdx.x * blockDim.x + threadIdx.x;
    if (idx < HN) {
        int h = idx / NST;
        float Ar = -expf(A_real_log[idx]);
        float Ai = A_imag[idx];
        float dt = expf(log_dt[h]);
        float dr = Ar * dt, di = Ai * dt;
        float er = expf(dr);
        float wr = er * cosf(di);
        float wi = er * sinf(di);
        float den = Ar * Ar + Ai * Ai;
        float a = wr - 1.0f, b = wi;
        float inv = 1.0f / den;
        float qr = (a * Ar + b * Ai) * inv;
        float qi = (b * Ar - a * Ai) * inv;
        wr_o[idx] = wr; wi_o[idx] = wi;
        cr_o[idx] = 2.0f * (C_re[idx] * qr - C_im[idx] * qi);
        ci_o[idx] = 2.0f * (C_re[idx] * qi + C_im[idx] * qr);
    }
    if (idx < 2 * H * HP) {
        int r = idx / HP, k = idx % HP;
        float v = (k < H) ? W[(size_t)r * H + k] : 0.0f;
        wbf[idx] = f2bf(v);
    }
}

// ---------------------------------------------------------------------------
// DPP helpers: sum across each 32-lane half; result lands in lanes 31 and 63.
// ---------------------------------------------------------------------------
template <int CTRL, int ROW_MASK>
__device__ __forceinline__ float dpp_add(float x) {
    int r = __builtin_amdgcn_update_dpp(0, __float_as_int(x), CTRL, ROW_MASK, 0xf, true);
    return x + __int_as_float(r);
}
__device__ __forceinline__ float reduce32_to_lane31(float p) {
    p = dpp_add<0x111, 0xf>(p);  // row_shr:1
    p = dpp_add<0x112, 0xf>(p);  // row_shr:2
    p = dpp_add<0x114, 0xf>(p);  // row_shr:4
    p = dpp_add<0x118, 0xf>(p);  // row_shr:8
    p = dpp_add<0x142, 0xa>(p);  // row_bcast:15 into rows 1,3
    return p;
}

__device__ __forceinline__ float gelu_tanh(float v) {
    const float c0 = 0.7978845608028654f;  // sqrt(2/pi)
    float t = tanhf(c0 * (v + 0.044715f * v * v * v));
    return 0.5f * v * (1.0f + t);
}

// ---------------------------------------------------------------------------
// Fused conv: one block = 2 channels, 1024 threads = 16 waves (one per chunk).
// Phase1: per-wave local scan -> end states in LDS.
// Phase2: wave 0 combines 16 chunk states per (ch,n) lane (block-level scan).
// Phase3: per-wave rescan with carry + C-dot DPP reduce + D-skip + gelu.
// Output written DIRECTLY transposed: ytb (L, HP) bf16.
// ---------------------------------------------------------------------------
__global__ __launch_bounds__(1024) void conv_fused(
    const float* __restrict__ z,       // (H,L) fp32
    const float* __restrict__ wr_,
    const float* __restrict__ wi_,
    const float* __restrict__ cr_,
    const float* __restrict__ ci_,
    const float* __restrict__ D_skip,
    ushort* __restrict__ ytb)          // (L,HP) bf16
{
    __shared__ float  zs[2][L];            // 16 KB
    __shared__ float  ber[NCHUNK][64];     // 4 KB
    __shared__ float  bei[NCHUNK][64];     // 4 KB
    __shared__ ushort ys[2][L];            // 8 KB

    const int tid  = threadIdx.x;
    const int wv   = tid >> 6;        // wave id = chunk id
    const int half = (tid >> 5) & 1;  // channel within pair
    const int ln   = tid & 31;        // state index n
    const int h0   = blockIdx.x * 2;
    const int hh   = (h0 + half < H) ? (h0 + half) : (H - 1);

    // stage both z rows: 4096 floats, one float4 per thread, coalesced
    {
        const int c   = tid >> 9;          // 0..1
        const int off = (tid & 511) * 4;
        const int hz  = (h0 + c < H) ? (h0 + c) : (H - 1);
        *(float4*)&zs[c][off] = *(const float4*)&z[(size_t)hz * L + off];
    }
    const int cidx = hh * NST + ln;
    const float wr = wr_[cidx], wi = wi_[cidx];
    const float cr = cr_[cidx], ci = ci_[cidx];
    const float Dh = D_skip[hh];
    __syncthreads();

    // phase 1: local scan of chunk wv (carry 0)
    float sr = 0.f, si = 0.f;
    {
        const float* zp = &zs[half][wv * TCH];
        #pragma unroll 4
        for (int l = 0; l < TCH; ++l) {
            float zl = zp[l];
            float nsr = fmaf(wr, sr, fmaf(-wi, si, zl));
            float nsi = fmaf(wr, si, wi * sr);
            sr = nsr; si = nsi;
        }
    }
    ber[wv][half * 32 + ln] = sr;
    bei[wv][half * 32 + ln] = si;
    __syncthreads();

    // phase 2: wave 0 lane (half,ln) combines the 16 chunk states
    if (wv == 0) {
        float wtr = wr, wti = wi;
        #pragma unroll
        for (int k = 0; k < 7; ++k) {      // w^128
            float nr = wtr * wtr - wti * wti;
            float ni = 2.0f * wtr * wti;
            wtr = nr; wti = ni;
        }
        float er = 0.f, ei = 0.f;
        const int j = half * 32 + ln;
        #pragma unroll
        for (int c = 0; c < NCHUNK; ++c) {
            float s_r = ber[c][j], s_i = bei[c][j];
            ber[c][j] = er; bei[c][j] = ei;   // carry-in for chunk c
            float ner = fmaf(wtr, er, fmaf(-wti, ei, s_r));
            float nei = fmaf(wtr, ei, fmaf(wti, er, s_i));
            er = ner; ei = nei;
        }
    }
    __syncthreads();

    // phase 3: rescan with carry + C-dot + reduce + D-skip + gelu
    sr = ber[wv][half * 32 + ln];
    si = bei[wv][half * 32 + ln];
    {
        const float* zp = &zs[half][wv * TCH];
        ushort* yp = &ys[half][wv * TCH];
        for (int l = 0; l < TCH; ++l) {
            float zl = zp[l];
            float nsr = fmaf(wr, sr, fmaf(-wi, si, zl));
            float nsi = fmaf(wr, si, wi * sr);
            sr = nsr; si = nsi;
            float p = fmaf(cr, sr, -ci * si);
            p = reduce32_to_lane31(p);
            if (ln == 31) yp[l] = f2bf(gelu_tanh(fmaf(Dh, zl, p)));
        }
    }
    __syncthreads();

    // transposed write: ytb[l*HP + h0] = (ys[0][l], ys[1][l]).
    // h0+1 may be the clamped duplicate at h=511; wbf[:,511]==0 nullifies it.
    {
        int l0 = tid * 2;
        #pragma unroll
        for (int j = 0; j < 2; ++j) {
            int l = l0 + j;
            ushort2 v;
            v.x = ys[0][l];
            v.y = ys[1][l];
            *(ushort2*)&ytb[(size_t)l * HP + h0] = v;
        }
    }
}

// ---------------------------------------------------------------------------
// MFMA GLU GEMM: C = wbf (2H,HP) . ytb^T (HP,L); GLU over gate pairs +
// residual. Block: 32 gate-paired rows x 64 cols, 4 waves (2x2), BK=64,
// XOR-swizzled LDS (kgrp ^= row&7) on write AND read -> conflict-free.
// ---------------------------------------------------------------------------
__global__ __launch_bounds__(256) void glu_mfma(
    const ushort* __restrict__ wbf,   // (2H, HP) bf16
    const ushort* __restrict__ ytb,   // (L, HP) bf16
    const float* __restrict__ bias,   // (2H)
    const float* __restrict__ zres,   // (H,L)
    float* __restrict__ out)          // (H,L)
{
    __shared__ ushort As1[32 * GBK];
    __shared__ ushort As2[32 * GBK];
    __shared__ ushort Bs[GBN * GBK];

    const int tid = threadIdx.x;
    const int h0 = blockIdx.y * 32;
    const int l0 = blockIdx.x * GBN;
    const int wid = tid >> 6;
    const int lane = tid & 63;
    const int wrow = (wid >> 1) * 16;
    const int wcol = (wid & 1) * 32;

    f32x4 acc1[2] = {{0.f,0.f,0.f,0.f},{0.f,0.f,0.f,0.f}};
    f32x4 acc2[2] = {{0.f,0.f,0.f,0.f},{0.f,0.f,0.f,0.f}};

    const int ar = tid >> 3;
    const int ak = tid & 7;
    const int hq1 = (h0 + ar < H) ? (h0 + ar) : (H - 1);
    const int hq2 = hq1 + H;
    const int aswz = ak ^ (ar & 7);

    for (int k0 = 0; k0 < HP; k0 += GBK) {
        short8 va1 = *(const short8*)&wbf[(size_t)hq1 * HP + k0 + ak * 8];
        short8 va2 = *(const short8*)&wbf[(size_t)hq2 * HP + k0 + ak * 8];
        *(short8*)&As1[ar * GBK + aswz * 8] = va1;
        *(short8*)&As2[ar * GBK + aswz * 8] = va2;
        #pragma unroll
        for (int j = 0; j < 2; ++j) {
            int idx = tid + j * 256;
            int br = idx >> 3;
            int bk = idx & 7;
            short8 vb = *(const short8*)&ytb[(size_t)(l0 + br) * HP + k0 + bk * 8];
            *(short8*)&Bs[br * GBK + (bk ^ (br & 7)) * 8] = vb;
        }
        __syncthreads();

        #pragma unroll
        for (int kk = 0; kk < 2; ++kk) {
            const int arow = wrow + (lane & 15);
            const int kg = kk * 4 + (lane >> 4);
            short8 a1 = *(const short8*)&As1[arow * GBK + (kg ^ (arow & 7)) * 8];
            short8 a2 = *(const short8*)&As2[arow * GBK + (kg ^ (arow & 7)) * 8];
            #pragma unroll
            for (int nf = 0; nf < 2; ++nf) {
                const int brow = wcol + nf * 16 + (lane & 15);
                short8 b = *(const short8*)&Bs[brow * GBK + (kg ^ (brow & 7)) * 8];
                acc1[nf] = __builtin_amdgcn_mfma_f32_16x16x32_bf16(a1, b, acc1[nf], 0, 0, 0);
                acc2[nf] = __builtin_amdgcn_mfma_f32_16x16x32_bf16(a2, b, acc2[nf], 0, 0, 0);
            }
        }
        __syncthreads();
    }

    // epilogue: C/D layout col=lane&15, row=(lane>>4)*4+reg  [m89-verified]
    #pragma unroll
    for (int nf = 0; nf < 2; ++nf) {
        const int col = l0 + wcol + nf * 16 + (lane & 15);
        #pragma unroll
        for (int r = 0; r < 4; ++r) {
            const int h = h0 + wrow + (lane >> 4) * 4 + r;
            if (h < H) {
                float v1 = acc1[nf][r] + bias[h];
                float v2 = acc2[nf][r] + bias[h + H];
                float g = v1 * (1.0f / (1.0f + expf(-v2)));
                out[(size_t)h * L + col] = g + zres[(size_t)h * L + col];
            }
        }
    }
}

// ---------------------------------------------------------------------------
// LN phase 1: per-stripe partial sums. Grid (L/64, NSTRIPE); block 64x4.
// ---------------------------------------------------------------------------
__global__ __launch_bounds__(256) void ln_stats(
    const float* __restrict__ zpre,
    float* __restrict__ psum, float* __restrict__ psq)
{
    __shared__ float ss[4][64];
    __shared__ float sg[4][64];
    const int tx = threadIdx.x & 63;
    const int ty = threadIdx.x >> 6;
    const int l = blockIdx.x * 64 + tx;
    const int s = blockIdx.y;
    const int hbase = s * 32;

    float sum = 0.f, sq = 0.f;
    #pragma unroll
    for (int j = 0; j < 8; ++j) {
        int h = hbase + ty + j * 4;
        if (h < H) {
            float v = zpre[(size_t)h * L + l];
            sum += v;
            sq = fmaf(v, v, sq);
        }
    }
    ss[ty][tx] = sum;
    sg[ty][tx] = sq;
    __syncthreads();
    if (ty == 0) {
        psum[(size_t)s * L + l] = ss[0][tx] + ss[1][tx] + ss[2][tx] + ss[3][tx];
        psq[(size_t)s * L + l]  = sg[0][tx] + sg[1][tx] + sg[2][tx] + sg[3][tx];
    }
}

// ---------------------------------------------------------------------------
// LN phase 2: fold partials -> mu/rstd per column; apply over this stripe.
// ---------------------------------------------------------------------------
__global__ __launch_bounds__(256) void ln_apply(
    const float* __restrict__ zpre,
    const float* __restrict__ psum, const float* __restrict__ psq,
    const float* __restrict__ g, const float* __restrict__ b,
    float* __restrict__ out)
{
    const int tx = threadIdx.x & 63;
    const int ty = threadIdx.x >> 6;
    const int l = blockIdx.x * 64 + tx;
    const int s = blockIdx.y;

    float S = 0.f, Q = 0.f;
    #pragma unroll
    for (int k = 0; k < NSTRIPE; ++k) {
        S += psum[(size_t)k * L + l];
        Q += psq[(size_t)k * L + l];
    }
    const float invH = 1.0f / (float)H;
    float mu = S * invH;
    float var = Q * invH - mu * mu;
    float rstd = rsqrtf(var + LN_EPS);

    const int hbase = s * 32;
    #pragma unroll
    for (int j = 0; j < 8; ++j) {
        int h = hbase + ty + j * 4;
        if (h < H) {
            float v = zpre[(size_t)h * L + l];
            out[(size_t)h * L + l] = (v - mu) * rstd * g[h] + b[h];
        }
    }
}

// ---------------------------------------------------------------------------
extern "C" void kernel_launch(void* const* d_in, const int* in_sizes, int n_in,
                              void* d_out, int out_size, void* d_ws, size_t ws_size,
                              hipStream_t stream) {
    const float* Z          = (const float*)d_in[0];
    const float* log_dt     = (const float*)d_in[1];
    const float* A_real_log = (const float*)d_in[2];
    const float* A_imag     = (const float*)d_in[3];
    const float* C_re       = (const float*)d_in[4];
    const float* C_im       = (const float*)d_in[5];
    const float* D_skip     = (const float*)d_in[6];
    const float* glu_w      = (const float*)d_in[7];
    const float* glu_b      = (const float*)d_in[8];
    const float* ln_g       = (const float*)d_in[9];
    const float* ln_b       = (const float*)d_in[10];

    float* out = (float*)d_out;
    float* ws  = (float*)d_ws;

    // fp32 regions (all multiples of 16 floats -> 16B-aligned)
    float* wr   = ws;
    float* wi   = wr + HN;
    float* cr   = wi + HN;
    float* ci   = cr + HN;
    float* zbuf = ci + HN;                        // (H,L) fp32
    float* psum = zbuf + (size_t)H * L;           // (NSTRIPE,L)
    float* psq  = psum + (size_t)NSTRIPE * L;
    // bf16 regions
    ushort* ytb = (ushort*)(psq + (size_t)NSTRIPE * L);   // (L,HP) bf16
    ushort* wbf = ytb + (size_t)L * HP;                   // (2H,HP) bf16

    pre_kernel<<<(2 * H * HP + 255) / 256, 256, 0, stream>>>(
        log_dt, A_real_log, A_imag, C_re, C_im, glu_w,
        wr, wi, cr, ci, wbf);

    const dim3 gg(L / GBN, (H + 31) / 32);
    const dim3 lg(L / 64, NSTRIPE);

    for (int layer = 0; layer < NLAYERS; ++layer) {
        const float* zcur = (layer == 0) ? Z : zbuf;

        conv_fused<<<(H + 1) / 2, 1024, 0, stream>>>(
            zcur, wr, wi, cr, ci, D_skip, ytb);
        glu_mfma<<<gg, 256, 0, stream>>>(wbf, ytb, glu_b, zcur, out);

        float* lnout = (layer < NLAYERS - 1) ? zbuf : out;
        ln_stats<<<lg, 256, 0, stream>>>(out, psum, psq);
        ln_apply<<<lg, 256, 0, stream>>>(out, psum, psq, ln_g, ln_b, lnout);
    }
}

// Round 8
// 240.268 us; speedup vs baseline: 1.4030x; 1.4030x over previous
//
#include <hip/hip_runtime.h>
#include <hip/hip_bf16.h>
#include <math.h>

#define H 511
#define L 2048
#define NST 32
#define NLAYERS 4
#define LN_EPS 1e-5f
#define NCH 32             // chunks per channel
#define TC (L / NCH)       // 64 steps per chunk
#define HN (H * NST)       // 16352
#define HP 512             // K padded
#define GBK 64
#define GBN 64
#define NSTRIPE 16         // LN h-stripes of 32

typedef __attribute__((ext_vector_type(8))) short short8;
typedef __attribute__((ext_vector_type(4))) float f32x4;

__device__ __forceinline__ ushort f2bf(float v) {
    __hip_bfloat16 b = __float2bfloat16(v);
    return *reinterpret_cast<ushort*>(&b);
}

// ---------------------------------------------------------------------------
// Merged precompute: per-(h,n) coefs (idx < HN) + W->bf16 pad (idx < 2H*HP).
// ---------------------------------------------------------------------------
__global__ __launch_bounds__(256) void pre_kernel(
    const float* __restrict__ log_dt,
    const float* __restrict__ A_real_log,
    const float* __restrict__ A_imag,
    const float* __restrict__ C_re,
    const float* __restrict__ C_im,
    const float* __restrict__ W,
    float* __restrict__ wr_o, float* __restrict__ wi_o,
    float* __restrict__ cr_o, float* __restrict__ ci_o,
    ushort* __restrict__ wbf)
{
    int idx = blockIdx.x * blockDim.x + threadIdx.x;
    if (idx < HN) {
        int h = idx / NST;
        float Ar = -expf(A_real_log[idx]);
        float Ai = A_imag[idx];
        float dt = expf(log_dt[h]);
        float dr = Ar * dt, di = Ai * dt;
        float er = expf(dr);
        float wr = er * cosf(di);
        float wi = er * sinf(di);
        float den = Ar * Ar + Ai * Ai;
        float a = wr - 1.0f, b = wi;
        float inv = 1.0f / den;
        float qr = (a * Ar + b * Ai) * inv;
        float qi = (b * Ar - a * Ai) * inv;
        wr_o[idx] = wr; wi_o[idx] = wi;
        cr_o[idx] = 2.0f * (C_re[idx] * qr - C_im[idx] * qi);
        ci_o[idx] = 2.0f * (C_re[idx] * qi + C_im[idx] * qr);
    }
    if (idx < 2 * H * HP) {
        int r = idx / HP, k = idx % HP;
        float v = (k < H) ? W[(size_t)r * H + k] : 0.0f;
        wbf[idx] = f2bf(v);
    }
}

// ---------------------------------------------------------------------------
// DPP helpers: sum across each 32-lane half; result lands in lanes 31 and 63.
// ---------------------------------------------------------------------------
template <int CTRL, int ROW_MASK>
__device__ __forceinline__ float dpp_add(float x) {
    int r = __builtin_amdgcn_update_dpp(0, __float_as_int(x), CTRL, ROW_MASK, 0xf, true);
    return x + __int_as_float(r);
}
__device__ __forceinline__ float reduce32_to_lane31(float p) {
    p = dpp_add<0x111, 0xf>(p);  // row_shr:1
    p = dpp_add<0x112, 0xf>(p);  // row_shr:2
    p = dpp_add<0x114, 0xf>(p);  // row_shr:4
    p = dpp_add<0x118, 0xf>(p);  // row_shr:8
    p = dpp_add<0x142, 0xa>(p);  // row_bcast:15 into rows 1,3
    return p;                    // lane31 = sum(0..31), lane63 = sum(32..63)
}

__device__ __forceinline__ float gelu_tanh(float v) {
    const float c0 = 0.7978845608028654f;  // sqrt(2/pi)
    float t = tanhf(c0 * (v + 0.044715f * v * v * v));
    return 0.5f * v * (1.0f + t);
}

// ---------------------------------------------------------------------------
// Fused conv v2: one block = ONE channel, 1024 threads = 16 waves = 32 chunks
// of 64 steps (each 32-lane half owns one chunk; lane = state n).
// Phase1: per-half local scan -> end states in LDS.
// Phase2: lanes tid<32 combine the 32 chunk states serially (w^64 carries).
// Phase3: rescan with carry + C-dot DPP reduce + D-skip -> ysf (preact, LDS).
// Epilogue: all-lane gelu + bf16 cast + coalesced row write to yb (H,L).
// ---------------------------------------------------------------------------
__global__ __launch_bounds__(1024) void conv_fused(
    const float* __restrict__ z,       // (H,L) fp32
    const float* __restrict__ wr_,
    const float* __restrict__ wi_,
    const float* __restrict__ cr_,
    const float* __restrict__ ci_,
    const float* __restrict__ D_skip,
    ushort* __restrict__ yb)           // (H,L) bf16
{
    __shared__ float zs[L];            // 8 KB
    __shared__ float ber[NCH][NST];    // 4 KB
    __shared__ float bei[NCH][NST];    // 4 KB
    __shared__ float ysf[L];           // 8 KB

    const int tid  = threadIdx.x;
    const int wv   = tid >> 6;          // wave 0..15
    const int half = (tid >> 5) & 1;
    const int ln   = tid & 31;          // state index n
    const int c    = wv * 2 + half;     // chunk 0..31
    const int h    = blockIdx.x;

    // stage z row: 2048 floats, one float2 per thread, coalesced
    *(float2*)&zs[tid * 2] = *(const float2*)&z[(size_t)h * L + tid * 2];

    const int cidx = h * NST + ln;
    const float wr = wr_[cidx], wi = wi_[cidx];
    const float cr = cr_[cidx], ci = ci_[cidx];
    const float Dh = D_skip[h];
    __syncthreads();

    // phase 1: local scan of chunk c (carry 0)
    float sr = 0.f, si = 0.f;
    {
        const float* zp = &zs[c * TC];
        #pragma unroll 4
        for (int l = 0; l < TC; ++l) {
            float zl = zp[l];
            float nsr = fmaf(wr, sr, fmaf(-wi, si, zl));
            float nsi = fmaf(wr, si, wi * sr);
            sr = nsr; si = nsi;
        }
    }
    ber[c][ln] = sr;
    bei[c][ln] = si;
    __syncthreads();

    // phase 2: threads 0..31 (lane n) combine the 32 chunk states
    if (tid < 32) {
        float wtr = wr, wti = wi;
        #pragma unroll
        for (int k = 0; k < 6; ++k) {      // w^64
            float nr = wtr * wtr - wti * wti;
            float ni = 2.0f * wtr * wti;
            wtr = nr; wti = ni;
        }
        float er = 0.f, ei = 0.f;
        #pragma unroll
        for (int cc = 0; cc < NCH; ++cc) {
            float s_r = ber[cc][tid], s_i = bei[cc][tid];
            ber[cc][tid] = er; bei[cc][tid] = ei;   // carry-in for chunk cc
            float ner = fmaf(wtr, er, fmaf(-wti, ei, s_r));
            float nei = fmaf(wtr, ei, fmaf(wti, er, s_i));
            er = ner; ei = nei;
        }
    }
    __syncthreads();

    // phase 3: rescan with carry + C-dot + reduce + D-skip (preactivation)
    sr = ber[c][ln];
    si = bei[c][ln];
    {
        const float* zp = &zs[c * TC];
        float* yp = &ysf[c * TC];
        for (int l = 0; l < TC; ++l) {
            float zl = zp[l];
            float nsr = fmaf(wr, sr, fmaf(-wi, si, zl));
            float nsi = fmaf(wr, si, wi * sr);
            sr = nsr; si = nsi;
            float p = fmaf(cr, sr, -ci * si);
            p = reduce32_to_lane31(p);
            if (ln == 31) yp[l] = fmaf(Dh, zl, p);
        }
    }
    __syncthreads();

    // epilogue: all lanes, gelu + bf16, coalesced ushort2 stores
    {
        ushort2 v;
        v.x = f2bf(gelu_tanh(ysf[tid * 2]));
        v.y = f2bf(gelu_tanh(ysf[tid * 2 + 1]));
        *(ushort2*)&yb[(size_t)h * L + tid * 2] = v;
    }
}

// ---------------------------------------------------------------------------
// Transpose y bf16 (H,L) -> ytb bf16 (L,HP), zero-filling h >= H.
// ---------------------------------------------------------------------------
__global__ __launch_bounds__(256) void ytr_kernel(
    const ushort* __restrict__ yb,
    ushort* __restrict__ ytb)
{
    __shared__ ushort t[32][34];
    const int tx = threadIdx.x;      // 0..31
    const int ty = threadIdx.y;      // 0..7
    const int l0 = blockIdx.x * 32;
    const int h0 = blockIdx.y * 32;
    #pragma unroll
    for (int j = 0; j < 4; ++j) {
        int h = h0 + ty + j * 8;
        ushort v = 0;
        if (h < H) v = yb[(size_t)h * L + l0 + tx];
        t[tx][ty + j * 8] = v;       // t[l_local][h_local]
    }
    __syncthreads();
    #pragma unroll
    for (int j = 0; j < 4; ++j) {
        int l = l0 + ty + j * 8;
        ytb[(size_t)l * HP + h0 + tx] = t[ty + j * 8][tx];
    }
}

// ---------------------------------------------------------------------------
// MFMA GLU GEMM: C = wbf (2H,HP) . ytb^T (HP,L); GLU over gate pairs +
// residual. Block: 32 gate-paired rows x 64 cols, 4 waves (2x2), BK=64,
// XOR-swizzled LDS (kgrp ^= row&7) on write AND read -> conflict-free.
// ---------------------------------------------------------------------------
__global__ __launch_bounds__(256) void glu_mfma(
    const ushort* __restrict__ wbf,   // (2H, HP) bf16
    const ushort* __restrict__ ytb,   // (L, HP) bf16
    const float* __restrict__ bias,   // (2H)
    const float* __restrict__ zres,   // (H,L)
    float* __restrict__ out)          // (H,L)
{
    __shared__ ushort As1[32 * GBK];
    __shared__ ushort As2[32 * GBK];
    __shared__ ushort Bs[GBN * GBK];

    const int tid = threadIdx.x;
    const int h0 = blockIdx.y * 32;
    const int l0 = blockIdx.x * GBN;
    const int wid = tid >> 6;
    const int lane = tid & 63;
    const int wrow = (wid >> 1) * 16;
    const int wcol = (wid & 1) * 32;

    f32x4 acc1[2] = {{0.f,0.f,0.f,0.f},{0.f,0.f,0.f,0.f}};
    f32x4 acc2[2] = {{0.f,0.f,0.f,0.f},{0.f,0.f,0.f,0.f}};

    const int ar = tid >> 3;
    const int ak = tid & 7;
    const int hq1 = (h0 + ar < H) ? (h0 + ar) : (H - 1);
    const int hq2 = hq1 + H;
    const int aswz = ak ^ (ar & 7);

    for (int k0 = 0; k0 < HP; k0 += GBK) {
        short8 va1 = *(const short8*)&wbf[(size_t)hq1 * HP + k0 + ak * 8];
        short8 va2 = *(const short8*)&wbf[(size_t)hq2 * HP + k0 + ak * 8];
        *(short8*)&As1[ar * GBK + aswz * 8] = va1;
        *(short8*)&As2[ar * GBK + aswz * 8] = va2;
        #pragma unroll
        for (int j = 0; j < 2; ++j) {
            int idx = tid + j * 256;
            int br = idx >> 3;
            int bk = idx & 7;
            short8 vb = *(const short8*)&ytb[(size_t)(l0 + br) * HP + k0 + bk * 8];
            *(short8*)&Bs[br * GBK + (bk ^ (br & 7)) * 8] = vb;
        }
        __syncthreads();

        #pragma unroll
        for (int kk = 0; kk < 2; ++kk) {
            const int arow = wrow + (lane & 15);
            const int kg = kk * 4 + (lane >> 4);
            short8 a1 = *(const short8*)&As1[arow * GBK + (kg ^ (arow & 7)) * 8];
            short8 a2 = *(const short8*)&As2[arow * GBK + (kg ^ (arow & 7)) * 8];
            #pragma unroll
            for (int nf = 0; nf < 2; ++nf) {
                const int brow = wcol + nf * 16 + (lane & 15);
                short8 b = *(const short8*)&Bs[brow * GBK + (kg ^ (brow & 7)) * 8];
                acc1[nf] = __builtin_amdgcn_mfma_f32_16x16x32_bf16(a1, b, acc1[nf], 0, 0, 0);
                acc2[nf] = __builtin_amdgcn_mfma_f32_16x16x32_bf16(a2, b, acc2[nf], 0, 0, 0);
            }
        }
        __syncthreads();
    }

    // epilogue: C/D layout col=lane&15, row=(lane>>4)*4+reg  [m89-verified]
    #pragma unroll
    for (int nf = 0; nf < 2; ++nf) {
        const int col = l0 + wcol + nf * 16 + (lane & 15);
        #pragma unroll
        for (int r = 0; r < 4; ++r) {
            const int h = h0 + wrow + (lane >> 4) * 4 + r;
            if (h < H) {
                float v1 = acc1[nf][r] + bias[h];
                float v2 = acc2[nf][r] + bias[h + H];
                float g = v1 * (1.0f / (1.0f + expf(-v2)));
                out[(size_t)h * L + col] = g + zres[(size_t)h * L + col];
            }
        }
    }
}

// ---------------------------------------------------------------------------
// LN phase 1: per-stripe partial sums. Grid (L/64, NSTRIPE); block 64x4.
// ---------------------------------------------------------------------------
__global__ __launch_bounds__(256) void ln_stats(
    const float* __restrict__ zpre,
    float* __restrict__ psum, float* __restrict__ psq)
{
    __shared__ float ss[4][64];
    __shared__ float sg[4][64];
    const int tx = threadIdx.x & 63;
    const int ty = threadIdx.x >> 6;
    const int l = blockIdx.x * 64 + tx;
    const int s = blockIdx.y;
    const int hbase = s * 32;

    float sum = 0.f, sq = 0.f;
    #pragma unroll
    for (int j = 0; j < 8; ++j) {
        int h = hbase + ty + j * 4;
        if (h < H) {
            float v = zpre[(size_t)h * L + l];
            sum += v;
            sq = fmaf(v, v, sq);
        }
    }
    ss[ty][tx] = sum;
    sg[ty][tx] = sq;
    __syncthreads();
    if (ty == 0) {
        psum[(size_t)s * L + l] = ss[0][tx] + ss[1][tx] + ss[2][tx] + ss[3][tx];
        psq[(size_t)s * L + l]  = sg[0][tx] + sg[1][tx] + sg[2][tx] + sg[3][tx];
    }
}

// ---------------------------------------------------------------------------
// LN phase 2: fold partials -> mu/rstd per column; apply over this stripe.
// ---------------------------------------------------------------------------
__global__ __launch_bounds__(256) void ln_apply(
    const float* __restrict__ zpre,
    const float* __restrict__ psum, const float* __restrict__ psq,
    const float* __restrict__ g, const float* __restrict__ b,
    float* __restrict__ out)
{
    const int tx = threadIdx.x & 63;
    const int ty = threadIdx.x >> 6;
    const int l = blockIdx.x * 64 + tx;
    const int s = blockIdx.y;

    float S = 0.f, Q = 0.f;
    #pragma unroll
    for (int k = 0; k < NSTRIPE; ++k) {
        S += psum[(size_t)k * L + l];
        Q += psq[(size_t)k * L + l];
    }
    const float invH = 1.0f / (float)H;
    float mu = S * invH;
    float var = Q * invH - mu * mu;
    float rstd = rsqrtf(var + LN_EPS);

    const int hbase = s * 32;
    #pragma unroll
    for (int j = 0; j < 8; ++j) {
        int h = hbase + ty + j * 4;
        if (h < H) {
            float v = zpre[(size_t)h * L + l];
            out[(size_t)h * L + l] = (v - mu) * rstd * g[h] + b[h];
        }
    }
}

// ---------------------------------------------------------------------------
extern "C" void kernel_launch(void* const* d_in, const int* in_sizes, int n_in,
                              void* d_out, int out_size, void* d_ws, size_t ws_size,
                              hipStream_t stream) {
    const float* Z          = (const float*)d_in[0];
    const float* log_dt     = (const float*)d_in[1];
    const float* A_real_log = (const float*)d_in[2];
    const float* A_imag     = (const float*)d_in[3];
    const float* C_re       = (const float*)d_in[4];
    const float* C_im       = (const float*)d_in[5];
    const float* D_skip     = (const float*)d_in[6];
    const float* glu_w      = (const float*)d_in[7];
    const float* glu_b      = (const float*)d_in[8];
    const float* ln_g       = (const float*)d_in[9];
    const float* ln_b       = (const float*)d_in[10];

    float* out = (float*)d_out;
    float* ws  = (float*)d_ws;

    // fp32 regions (all multiples of 16 floats -> 16B-aligned)
    float* wr   = ws;
    float* wi   = wr + HN;
    float* cr   = wi + HN;
    float* ci   = cr + HN;
    float* zbuf = ci + HN;                        // (H,L) fp32
    float* psum = zbuf + (size_t)H * L;           // (NSTRIPE,L)
    float* psq  = psum + (size_t)NSTRIPE * L;
    // bf16 regions
    ushort* yb  = (ushort*)(psq + (size_t)NSTRIPE * L);   // (H,L) bf16
    ushort* ytb = yb + (size_t)H * L;                     // (L,HP) bf16
    ushort* wbf = ytb + (size_t)L * HP;                   // (2H,HP) bf16

    pre_kernel<<<(2 * H * HP + 255) / 256, 256, 0, stream>>>(
        log_dt, A_real_log, A_imag, C_re, C_im, glu_w,
        wr, wi, cr, ci, wbf);

    const dim3 tg(L / 32, HP / 32);
    const dim3 tb(32, 8);
    const dim3 gg(L / GBN, (H + 31) / 32);
    const dim3 lg(L / 64, NSTRIPE);

    for (int layer = 0; layer < NLAYERS; ++layer) {
        const float* zcur = (layer == 0) ? Z : zbuf;

        conv_fused<<<H, 1024, 0, stream>>>(
            zcur, wr, wi, cr, ci, D_skip, yb);
        ytr_kernel<<<tg, tb, 0, stream>>>(yb, ytb);
        glu_mfma<<<gg, 256, 0, stream>>>(wbf, ytb, glu_b, zcur, out);

        float* lnout = (layer < NLAYERS - 1) ? zbuf : out;
        ln_stats<<<lg, 256, 0, stream>>>(out, psum, psq);
        ln_apply<<<lg, 256, 0, stream>>>(out, psum, psq, ln_g, ln_b, lnout);
    }
}

// Round 10
// 222.586 us; speedup vs baseline: 1.5145x; 1.0794x over previous
//
#include <hip/hip_runtime.h>
#include <hip/hip_bf16.h>
#include <math.h>

#define H 511
#define L 2048
#define NST 32
#define NLAYERS 4
#define LN_EPS 1e-5f
#define NCH 32             // chunks per channel (conv)
#define TC (L / NCH)       // 64 steps per chunk
#define HN (H * NST)       // 16352
#define HP 512             // K padded
#define GBK 64
#define GBN 64
#define NSTRIPE 16         // LN h-stripes of 32

typedef __attribute__((ext_vector_type(8))) short short8;
typedef __attribute__((ext_vector_type(4))) float f32x4;

__device__ __forceinline__ ushort f2bf(float v) {
    __hip_bfloat16 b = __float2bfloat16(v);
    return *reinterpret_cast<ushort*>(&b);
}

// ---------------------------------------------------------------------------
// Merged precompute: per-(h,n) coefs (idx < HN) + W->bf16 pad (idx < 2H*HP).
// ---------------------------------------------------------------------------
__global__ __launch_bounds__(256) void pre_kernel(
    const float* __restrict__ log_dt,
    const float* __restrict__ A_real_log,
    const float* __restrict__ A_imag,
    const float* __restrict__ C_re,
    const float* __restrict__ C_im,
    const float* __restrict__ W,
    float* __restrict__ wr_o, float* __restrict__ wi_o,
    float* __restrict__ cr_o, float* __restrict__ ci_o,
    ushort* __restrict__ wbf)
{
    int idx = blockIdx.x * blockDim.x + threadIdx.x;
    if (idx < HN) {
        int h = idx / NST;
        float Ar = -expf(A_real_log[idx]);
        float Ai = A_imag[idx];
        float dt = expf(log_dt[h]);
        float dr = Ar * dt, di = Ai * dt;
        float er = expf(dr);
        float wr = er * cosf(di);
        float wi = er * sinf(di);
        float den = Ar * Ar + Ai * Ai;
        float a = wr - 1.0f, b = wi;
        float inv = 1.0f / den;
        float qr = (a * Ar + b * Ai) * inv;
        float qi = (b * Ar - a * Ai) * inv;
        wr_o[idx] = wr; wi_o[idx] = wi;
        cr_o[idx] = 2.0f * (C_re[idx] * qr - C_im[idx] * qi);
        ci_o[idx] = 2.0f * (C_re[idx] * qi + C_im[idx] * qr);
    }
    if (idx < 2 * H * HP) {
        int r = idx / HP, k = idx % HP;
        float v = (k < H) ? W[(size_t)r * H + k] : 0.0f;
        wbf[idx] = f2bf(v);
    }
}

// ---------------------------------------------------------------------------
// DPP helpers: sum across each 32-lane half; result lands in lanes 31 and 63.
// ---------------------------------------------------------------------------
template <int CTRL, int ROW_MASK>
__device__ __forceinline__ float dpp_add(float x) {
    int r = __builtin_amdgcn_update_dpp(0, __float_as_int(x), CTRL, ROW_MASK, 0xf, true);
    return x + __int_as_float(r);
}
__device__ __forceinline__ float reduce32_to_lane31(float p) {
    p = dpp_add<0x111, 0xf>(p);  // row_shr:1
    p = dpp_add<0x112, 0xf>(p);  // row_shr:2
    p = dpp_add<0x114, 0xf>(p);  // row_shr:4
    p = dpp_add<0x118, 0xf>(p);  // row_shr:8
    p = dpp_add<0x142, 0xa>(p);  // row_bcast:15 into rows 1,3
    return p;                    // lane31 = sum(0..31), lane63 = sum(32..63)
}

__device__ __forceinline__ float gelu_tanh(float v) {
    const float c0 = 0.7978845608028654f;  // sqrt(2/pi)
    float t = tanhf(c0 * (v + 0.044715f * v * v * v));
    return 0.5f * v * (1.0f + t);
}

// ---------------------------------------------------------------------------
// Fused conv (round-8 proven): one block = ONE channel, 1024 thr = 32 chunks
// of 64 steps. Local scan -> LDS combine -> rescan -> gelu epilogue -> yb.
// ---------------------------------------------------------------------------
__global__ __launch_bounds__(1024) void conv_fused(
    const float* __restrict__ z,       // (H,L) fp32
    const float* __restrict__ wr_,
    const float* __restrict__ wi_,
    const float* __restrict__ cr_,
    const float* __restrict__ ci_,
    const float* __restrict__ D_skip,
    ushort* __restrict__ yb)           // (H,L) bf16
{
    __shared__ float zs[L];            // 8 KB
    __shared__ float ber[NCH][NST];    // 4 KB
    __shared__ float bei[NCH][NST];    // 4 KB
    __shared__ float ysf[L];           // 8 KB

    const int tid  = threadIdx.x;
    const int wv   = tid >> 6;          // wave 0..15
    const int half = (tid >> 5) & 1;
    const int ln   = tid & 31;          // state index n
    const int c    = wv * 2 + half;     // chunk 0..31
    const int h    = blockIdx.x;

    *(float2*)&zs[tid * 2] = *(const float2*)&z[(size_t)h * L + tid * 2];

    const int cidx = h * NST + ln;
    const float wr = wr_[cidx], wi = wi_[cidx];
    const float cr = cr_[cidx], ci = ci_[cidx];
    const float Dh = D_skip[h];
    __syncthreads();

    // phase 1: local scan of chunk c (carry 0)
    float sr = 0.f, si = 0.f;
    {
        const float* zp = &zs[c * TC];
        #pragma unroll 4
        for (int l = 0; l < TC; ++l) {
            float zl = zp[l];
            float nsr = fmaf(wr, sr, fmaf(-wi, si, zl));
            float nsi = fmaf(wr, si, wi * sr);
            sr = nsr; si = nsi;
        }
    }
    ber[c][ln] = sr;
    bei[c][ln] = si;
    __syncthreads();

    // phase 2: threads 0..31 (lane n) combine the 32 chunk states
    if (tid < 32) {
        float wtr = wr, wti = wi;
        #pragma unroll
        for (int k = 0; k < 6; ++k) {      // w^64
            float nr = wtr * wtr - wti * wti;
            float ni = 2.0f * wtr * wti;
            wtr = nr; wti = ni;
        }
        float er = 0.f, ei = 0.f;
        #pragma unroll
        for (int cc = 0; cc < NCH; ++cc) {
            float s_r = ber[cc][tid], s_i = bei[cc][tid];
            ber[cc][tid] = er; bei[cc][tid] = ei;   // carry-in for chunk cc
            float ner = fmaf(wtr, er, fmaf(-wti, ei, s_r));
            float nei = fmaf(wtr, ei, fmaf(wti, er, s_i));
            er = ner; ei = nei;
        }
    }
    __syncthreads();

    // phase 3: rescan with carry + C-dot + reduce + D-skip (preactivation)
    sr = ber[c][ln];
    si = bei[c][ln];
    {
        const float* zp = &zs[c * TC];
        float* yp = &ysf[c * TC];
        for (int l = 0; l < TC; ++l) {
            float zl = zp[l];
            float nsr = fmaf(wr, sr, fmaf(-wi, si, zl));
            float nsi = fmaf(wr, si, wi * sr);
            sr = nsr; si = nsi;
            float p = fmaf(cr, sr, -ci * si);
            p = reduce32_to_lane31(p);
            if (ln == 31) yp[l] = fmaf(Dh, zl, p);
        }
    }
    __syncthreads();

    // epilogue: all lanes, gelu + bf16, coalesced ushort2 stores
    {
        ushort2 v;
        v.x = f2bf(gelu_tanh(ysf[tid * 2]));
        v.y = f2bf(gelu_tanh(ysf[tid * 2 + 1]));
        *(ushort2*)&yb[(size_t)h * L + tid * 2] = v;
    }
}

// ---------------------------------------------------------------------------
// MFMA GLU GEMM + fused LN-stats.
// B tile staged DIRECTLY from yb (H,L) via in-kernel ytr-style transpose:
//   4 teams of 64 threads, each owns a 32x32 subtile:
//     load yb rows (k) l-contiguous -> scatter into padded temp[l][k]
//     sync; ds_read_b128 k-contiguous from temp -> swizzled Bs write.
// Epilogue: GLU+residual -> out, plus per-(32h-stripe, l) partial sum/sumsq
// written to psum/psq (NSTRIPE,L) -- replaces the ln_stats kernel.
// ---------------------------------------------------------------------------
__global__ __launch_bounds__(256) void glu_mfma(
    const ushort* __restrict__ wbf,   // (2H, HP) bf16
    const ushort* __restrict__ yb,    // (H, L) bf16
    const float* __restrict__ bias,   // (2H)
    const float* __restrict__ zres,   // (H,L)
    float* __restrict__ out,          // (H,L)
    float* __restrict__ psum,         // (NSTRIPE,L)
    float* __restrict__ psq)          // (NSTRIPE,L)
{
    __shared__ ushort As1[32 * GBK];       // 4 KB
    __shared__ ushort As2[32 * GBK];       // 4 KB
    __shared__ ushort Bs[GBN * GBK];       // 8 KB
    __shared__ ushort tempT[4][32 * 40];   // 10 KB, pad 40 -> 16B-aligned rows
    __shared__ float  sls[2][64];          // ln partials (wrow-half x col)
    __shared__ float  slq[2][64];

    const int tid = threadIdx.x;
    const int h0 = blockIdx.y * 32;
    const int l0 = blockIdx.x * GBN;
    const int wid = tid >> 6;
    const int lane = tid & 63;
    const int wrow = (wid >> 1) * 16;
    const int wcol = (wid & 1) * 32;

    f32x4 acc1[2] = {{0.f,0.f,0.f,0.f},{0.f,0.f,0.f,0.f}};
    f32x4 acc2[2] = {{0.f,0.f,0.f,0.f},{0.f,0.f,0.f,0.f}};

    // A staging indices
    const int ar = tid >> 3;
    const int ak = tid & 7;
    const int hq1 = (h0 + ar < H) ? (h0 + ar) : (H - 1);
    const int hq2 = hq1 + H;
    const int aswz = ak ^ (ar & 7);

    // B staging indices (team transpose)
    const int tm   = tid >> 6;            // team 0..3
    const int t64  = tid & 63;
    const int ksub = (tm & 1) * 32;
    const int lsub = (tm >> 1) * 32;
    const int bkl  = t64 >> 1;            // k-local row 0..31
    const int bhalf= t64 & 1;             // l half (0: l 0..15, 1: 16..31)
    const int blr  = t64 >> 1;            // read-out: l-local row 0..31
    const int bkh  = t64 & 1;             // read-out: k half

    for (int k0 = 0; k0 < HP; k0 += GBK) {
        // ---- A tiles (both gates), unchanged ----
        {
            short8 va1 = *(const short8*)&wbf[(size_t)hq1 * HP + k0 + ak * 8];
            short8 va2 = *(const short8*)&wbf[(size_t)hq2 * HP + k0 + ak * 8];
            *(short8*)&As1[ar * GBK + aswz * 8] = va1;
            *(short8*)&As2[ar * GBK + aswz * 8] = va2;
        }
        // ---- B load: yb row (k) -> temp[l][k] scatter ----
        {
            const int kg = k0 + ksub + bkl;      // global k = h index of y
            short8 v0 = {0,0,0,0,0,0,0,0}, v1 = {0,0,0,0,0,0,0,0};
            if (kg < H) {
                const ushort* row = &yb[(size_t)kg * L + l0 + lsub + bhalf * 16];
                v0 = *(const short8*)&row[0];
                v1 = *(const short8*)&row[8];
            }
            ushort* tp = &tempT[tm][0];
            #pragma unroll
            for (int j = 0; j < 8; ++j)
                tp[(bhalf * 16 + j) * 40 + bkl] = (ushort)v0[j];
            #pragma unroll
            for (int j = 0; j < 8; ++j)
                tp[(bhalf * 16 + 8 + j) * 40 + bkl] = (ushort)v1[j];
        }
        __syncthreads();
        // ---- B transpose out: temp -> Bs (swizzled) ----
        {
            const ushort* tp = &tempT[tm][0];
            short8 b0 = *(const short8*)&tp[blr * 40 + bkh * 16];
            short8 b1 = *(const short8*)&tp[blr * 40 + bkh * 16 + 8];
            const int L_ = lsub + blr;                 // l-row 0..63
            const int kg0 = (ksub >> 3) + bkh * 2;     // k-group of first octet
            *(short8*)&Bs[L_ * GBK + ((kg0    ) ^ (L_ & 7)) * 8] = b0;
            *(short8*)&Bs[L_ * GBK + ((kg0 + 1) ^ (L_ & 7)) * 8] = b1;
        }
        __syncthreads();

        // ---- MFMA (unchanged) ----
        #pragma unroll
        for (int kk = 0; kk < 2; ++kk) {
            const int arow = wrow + (lane & 15);
            const int kg = kk * 4 + (lane >> 4);
            short8 a1 = *(const short8*)&As1[arow * GBK + (kg ^ (arow & 7)) * 8];
            short8 a2 = *(const short8*)&As2[arow * GBK + (kg ^ (arow & 7)) * 8];
            #pragma unroll
            for (int nf = 0; nf < 2; ++nf) {
                const int brow = wcol + nf * 16 + (lane & 15);
                short8 b = *(const short8*)&Bs[brow * GBK + (kg ^ (brow & 7)) * 8];
                acc1[nf] = __builtin_amdgcn_mfma_f32_16x16x32_bf16(a1, b, acc1[nf], 0, 0, 0);
                acc2[nf] = __builtin_amdgcn_mfma_f32_16x16x32_bf16(a2, b, acc2[nf], 0, 0, 0);
            }
        }
        __syncthreads();
    }

    // ---- epilogue: GLU + residual -> out, plus LN partial stats ----
    float ps[2] = {0.f, 0.f}, pq[2] = {0.f, 0.f};
    #pragma unroll
    for (int nf = 0; nf < 2; ++nf) {
        const int col = l0 + wcol + nf * 16 + (lane & 15);
        #pragma unroll
        for (int r = 0; r < 4; ++r) {
            const int h = h0 + wrow + (lane >> 4) * 4 + r;
            if (h < H) {
                float v1 = acc1[nf][r] + bias[h];
                float v2 = acc2[nf][r] + bias[h + H];
                float o = v1 * (1.0f / (1.0f + expf(-v2))) + zres[(size_t)h * L + col];
                out[(size_t)h * L + col] = o;
                ps[nf] += o;
                pq[nf] = fmaf(o, o, pq[nf]);
            }
        }
    }
    // reduce the 4 lanes sharing a column (lane ^ 16, lane ^ 32)
    #pragma unroll
    for (int nf = 0; nf < 2; ++nf) {
        ps[nf] += __shfl_xor(ps[nf], 16, 64);
        ps[nf] += __shfl_xor(ps[nf], 32, 64);
        pq[nf] += __shfl_xor(pq[nf], 16, 64);
        pq[nf] += __shfl_xor(pq[nf], 32, 64);
        if ((lane >> 4) == 0) {
            int cl = wcol + nf * 16 + lane;    // col-local 0..63
            sls[wid >> 1][cl] = ps[nf];
            slq[wid >> 1][cl] = pq[nf];
        }
    }
    __syncthreads();
    if (tid < 64) {
        psum[(size_t)blockIdx.y * L + l0 + tid] = sls[0][tid] + sls[1][tid];
        psq [(size_t)blockIdx.y * L + l0 + tid] = slq[0][tid] + slq[1][tid];
    }
}

// ---------------------------------------------------------------------------
// LN phase 2 (unchanged): fold partials -> mu/rstd per column; apply stripe.
// ---------------------------------------------------------------------------
__global__ __launch_bounds__(256) void ln_apply(
    const float* __restrict__ zpre,
    const float* __restrict__ psum, const float* __restrict__ psq,
    const float* __restrict__ g, const float* __restrict__ b,
    float* __restrict__ out)
{
    const int tx = threadIdx.x & 63;
    const int ty = threadIdx.x >> 6;
    const int l = blockIdx.x * 64 + tx;
    const int s = blockIdx.y;

    float S = 0.f, Q = 0.f;
    #pragma unroll
    for (int k = 0; k < NSTRIPE; ++k) {
        S += psum[(size_t)k * L + l];
        Q += psq[(size_t)k * L + l];
    }
    const float invH = 1.0f / (float)H;
    float mu = S * invH;
    float var = Q * invH - mu * mu;
    float rstd = rsqrtf(var + LN_EPS);

    const int hbase = s * 32;
    #pragma unroll
    for (int j = 0; j < 8; ++j) {
        int h = hbase + ty + j * 4;
        if (h < H) {
            float v = zpre[(size_t)h * L + l];
            out[(size_t)h * L + l] = (v - mu) * rstd * g[h] + b[h];
        }
    }
}

// ---------------------------------------------------------------------------
extern "C" void kernel_launch(void* const* d_in, const int* in_sizes, int n_in,
                              void* d_out, int out_size, void* d_ws, size_t ws_size,
                              hipStream_t stream) {
    const float* Z          = (const float*)d_in[0];
    const float* log_dt     = (const float*)d_in[1];
    const float* A_real_log = (const float*)d_in[2];
    const float* A_imag     = (const float*)d_in[3];
    const float* C_re       = (const float*)d_in[4];
    const float* C_im       = (const float*)d_in[5];
    const float* D_skip     = (const float*)d_in[6];
    const float* glu_w      = (const float*)d_in[7];
    const float* glu_b      = (const float*)d_in[8];
    const float* ln_g       = (const float*)d_in[9];
    const float* ln_b       = (const float*)d_in[10];

    float* out = (float*)d_out;
    float* ws  = (float*)d_ws;

    float* wr   = ws;
    float* wi   = wr + HN;
    float* cr   = wi + HN;
    float* ci   = cr + HN;
    float* zbuf = ci + HN;                        // (H,L) fp32
    float* psum = zbuf + (size_t)H * L;           // (NSTRIPE,L)
    float* psq  = psum + (size_t)NSTRIPE * L;
    ushort* yb  = (ushort*)(psq + (size_t)NSTRIPE * L);   // (H,L) bf16
    ushort* wbf = yb + (size_t)H * L;                     // (2H,HP) bf16

    pre_kernel<<<(2 * H * HP + 255) / 256, 256, 0, stream>>>(
        log_dt, A_real_log, A_imag, C_re, C_im, glu_w,
        wr, wi, cr, ci, wbf);

    const dim3 gg(L / GBN, (H + 31) / 32);
    const dim3 lg(L / 64, NSTRIPE);

    for (int layer = 0; layer < NLAYERS; ++layer) {
        const float* zcur = (layer == 0) ? Z : zbuf;

        conv_fused<<<H, 1024, 0, stream>>>(
            zcur, wr, wi, cr, ci, D_skip, yb);
        glu_mfma<<<gg, 256, 0, stream>>>(wbf, yb, glu_b, zcur, out, psum, psq);

        float* lnout = (layer < NLAYERS - 1) ? zbuf : out;
        ln_apply<<<lg, 256, 0, stream>>>(out, psum, psq, ln_g, ln_b, lnout);
    }
}